// Round 6
// baseline (326.238 us; speedup 1.0000x reference)
//
#include <hip/hip_runtime.h>

#define D 2048
#define R 64
#define NTOK 16384
#define KT 256              // k-tile per iteration (floats)
#define KW 512              // K slice per wave (2 tiles)
#define HROW 264            // h row stride in bf16 (256 + 8 pad)
#define PROW 68             // P partial row stride in fp32 (64 + 4 pad)
#define STGROW 516          // epilogue chunk staging row stride in fp32 (512 + 4 pad)
#define WREG 8448           // per-wave LDS region bytes (16*HROW*2)

typedef float f32x4 __attribute__((ext_vector_type(4)));
typedef short s16x8 __attribute__((ext_vector_type(8)));

__device__ inline unsigned short f2bf(float f) {
    union { float f; unsigned int u; } c; c.f = f;
    unsigned int u = c.u;
    return (unsigned short)((u + 0x7fffu + ((u >> 16) & 1u)) >> 16);  // RNE
}
__device__ inline ushort4 pack4(float4 v) {
    ushort4 p;
    p.x = f2bf(v.x); p.y = f2bf(v.y); p.z = f2bf(v.z); p.w = f2bf(v.w);
    return p;
}

// ---- prep 1: repack wd, wu into bf16 MFMA B-fragment order ----
__global__ __launch_bounds__(256)
void convert_pack(const float* __restrict__ wd, const float* __restrict__ wu,
                  unsigned short* __restrict__ wdbp, unsigned short* __restrict__ wubp) {
    const int fid  = blockIdx.x * 256 + threadIdx.x;   // 0..16383
    const int lane = fid & 63;
    const int l15  = lane & 15;
    const int quad = lane >> 4;
    {
        const int nt = (fid >> 6) & 3;
        const int ks = fid >> 8;                       // 0..63
        const int r  = nt * 16 + l15;
        const int k0 = ks * 32 + quad * 8;
        const float4 a0 = *(const float4*)(wd + (size_t)r * D + k0);
        const float4 a1 = *(const float4*)(wd + (size_t)r * D + k0 + 4);
        *(ushort4*)(wdbp + (size_t)fid * 8)     = pack4(a0);
        *(ushort4*)(wdbp + (size_t)fid * 8 + 4) = pack4(a1);
    }
    {
        const int s   = (fid >> 6) & 1;
        const int nt2 = fid >> 7;                      // 0..127
        const int dd  = nt2 * 16 + l15;
        const int r0  = s * 32 + quad * 8;
        const float4 b0 = *(const float4*)(wu + (size_t)dd * R + r0);
        const float4 b1 = *(const float4*)(wu + (size_t)dd * R + r0 + 4);
        *(ushort4*)(wubp + (size_t)fid * 8)     = pack4(b0);
        *(ushort4*)(wubp + (size_t)fid * 8 + 4) = pack4(b1);
    }
}

// ---- prep 2: u[r] = wd[r,:]·gamma ; cb[r] = wd[r,:]·beta + bd[r] ----
__global__ __launch_bounds__(256)
void prep_uc(const float* __restrict__ wd, const float* __restrict__ gamma,
             const float* __restrict__ beta, const float* __restrict__ bd,
             float* __restrict__ u, float* __restrict__ cb) {
    const int r = blockIdx.x;
    const int tid = threadIdx.x;
    const int lane = tid & 63, wave = tid >> 6;
    float su = 0.f, sc = 0.f;
    for (int i = tid; i < D / 4; i += 256) {
        const float4 w  = ((const float4*)(wd + (size_t)r * D))[i];
        const float4 g  = ((const float4*)gamma)[i];
        const float4 be = ((const float4*)beta)[i];
        su += w.x * g.x + w.y * g.y + w.z * g.z + w.w * g.w;
        sc += w.x * be.x + w.y * be.y + w.z * be.z + w.w * be.w;
    }
    #pragma unroll
    for (int off = 32; off >= 1; off >>= 1) {
        su += __shfl_xor(su, off, 64);
        sc += __shfl_xor(sc, off, 64);
    }
    __shared__ float red[2][4];
    if (lane == 0) { red[0][wave] = su; red[1][wave] = sc; }
    __syncthreads();
    if (tid == 0) {
        u[r]  = red[0][0] + red[0][1] + red[0][2] + red[0][3];
        cb[r] = red[1][0] + red[1][1] + red[1][2] + red[1][3] + bd[r];
    }
}

// ---- fused adapter: 256 threads, 4 waves K/N-split over 16 tokens ----
__global__ __launch_bounds__(256, 4)
void adapter_mfma(const float* __restrict__ x,
                  const float* __restrict__ gamma,
                  const unsigned short* __restrict__ wdbp,  // frag-major (R,D) bf16
                  const unsigned short* __restrict__ wubp,  // frag-major (D,R) bf16
                  const float* __restrict__ u,
                  const float* __restrict__ cb,
                  const float* __restrict__ bu,
                  const float* __restrict__ scale_p,
                  float* __restrict__ out)
{
    // per-wave h (bf16) / P partial (fp32) regions; later overlaid by the
    // block-shared per-chunk staging buffer stg[16][STGROW] (33024 B <= 33792 B)
    __shared__ __align__(16) unsigned char smem[4 * WREG];
    __shared__ float s_lds[4][16];
    __shared__ float ss_lds[4][16];

    const int tid  = threadIdx.x;
    const int wave = tid >> 6;
    const int lane = tid & 63;
    const int l15  = lane & 15;
    const int quad = lane >> 4;
    const int tok0 = blockIdx.x * 16;

    unsigned short* h  = (unsigned short*)(smem + wave * WREG);
    float*          pw = (float*)(smem + wave * WREG);

    float sm[16], ssm[16];
    #pragma unroll
    for (int m = 0; m < 16; ++m) { sm[m] = 0.f; ssm[m] = 0.f; }

    f32x4 acc[4];
    #pragma unroll
    for (int nt = 0; nt < 4; ++nt) acc[nt] = (f32x4){0.f, 0.f, 0.f, 0.f};

    // ---- single pass over this wave's K slice: stats + gamma*x (bf16) + MFMA ----
    const int kbase = wave * KW;
    #pragma unroll
    for (int kt = 0; kt < KW / KT; ++kt) {
        const int kb = kbase + kt * KT;
        const float4 g4 = ((const float4*)gamma)[(kb >> 2) + lane];
        #pragma unroll
        for (int m = 0; m < 16; ++m) {
            const float4 v = ((const float4*)(x + (size_t)(tok0 + m) * D + kb))[lane];
            sm[m]  += (v.x + v.y) + (v.z + v.w);
            ssm[m] += (v.x * v.x + v.y * v.y) + (v.z * v.z + v.w * v.w);
            float4 hg;
            hg.x = v.x * g4.x; hg.y = v.y * g4.y; hg.z = v.z * g4.z; hg.w = v.w * g4.w;
            *(ushort4*)&h[m * HROW + lane * 4] = pack4(hg);
        }
        const int ks0 = (kb >> 5);
        #pragma unroll
        for (int s = 0; s < KT / 32; ++s) {
            const s16x8 a = *(const s16x8*)&h[l15 * HROW + s * 32 + quad * 8];
            #pragma unroll
            for (int nt = 0; nt < 4; ++nt) {
                const s16x8 b = ((const s16x8*)wdbp)[((ks0 + s) * 4 + nt) * 64 + lane];
                acc[nt] = __builtin_amdgcn_mfma_f32_16x16x32_bf16(a, b, acc[nt], 0, 0, 0);
            }
        }
    }

    // ---- reduce per-token stats within wave, publish partials ----
    #pragma unroll
    for (int m = 0; m < 16; ++m) {
        float s = sm[m], q = ssm[m];
        #pragma unroll
        for (int off = 32; off >= 1; off >>= 1) {
            s += __shfl_xor(s, off, 64);
            q += __shfl_xor(q, off, 64);
        }
        sm[m] = s; ssm[m] = q;
    }
    if (lane == 0) {
        #pragma unroll
        for (int m = 0; m < 16; ++m) { s_lds[wave][m] = sm[m]; ss_lds[wave][m] = ssm[m]; }
    }

    // ---- publish P partial (overwrites own h region; per-wave DS in-order) ----
    #pragma unroll
    for (int nt = 0; nt < 4; ++nt)
        #pragma unroll
        for (int reg = 0; reg < 4; ++reg)
            pw[(quad * 4 + reg) * PROW + nt * 16 + l15] = acc[nt][reg];

    __syncthreads();

    // ---- finalize stats for token m = l15 ----
    const float s_tot  = s_lds[0][l15] + s_lds[1][l15] + s_lds[2][l15] + s_lds[3][l15];
    const float ss_tot = ss_lds[0][l15] + ss_lds[1][l15] + ss_lds[2][l15] + ss_lds[3][l15];
    const float mu = s_tot * (1.0f / D);
    const float rs = rsqrtf(ss_tot * (1.0f / D) - mu * mu + 1e-5f);

    // ---- build up-proj A-frags: down[m=l15][k=r] = relu(rs*(P - mu*u) + cb) ----
    s16x8 afrag[2];
    #pragma unroll
    for (int f = 0; f < 2; ++f) {
        const int rb = f * 32 + quad * 8;
        float ps[8];
        #pragma unroll
        for (int e = 0; e < 8; ++e) ps[e] = 0.f;
        #pragma unroll
        for (int w = 0; w < 4; ++w) {
            const float* pv = (const float*)(smem + w * WREG);
            const f32x4 pA = *(const f32x4*)&pv[l15 * PROW + rb];
            const f32x4 pB = *(const f32x4*)&pv[l15 * PROW + rb + 4];
            ps[0] += pA[0]; ps[1] += pA[1]; ps[2] += pA[2]; ps[3] += pA[3];
            ps[4] += pB[0]; ps[5] += pB[1]; ps[6] += pB[2]; ps[7] += pB[3];
        }
        const f32x4 u0 = *(const f32x4*)&u[rb];
        const f32x4 u1 = *(const f32x4*)&u[rb + 4];
        const f32x4 c0 = *(const f32x4*)&cb[rb];
        const f32x4 c1 = *(const f32x4*)&cb[rb + 4];
        s16x8 af;
        #pragma unroll
        for (int e = 0; e < 4; ++e) {
            const float v0 = fmaxf(rs * (ps[e]     - mu * u0[e]) + c0[e], 0.f);
            const float v1 = fmaxf(rs * (ps[4 + e] - mu * u1[e]) + c1[e], 0.f);
            af[e]     = (short)f2bf(v0);
            af[4 + e] = (short)f2bf(v1);
        }
        afrag[f] = af;
    }

    __syncthreads();   // all waves done reading P partials before staging overlay

    // ---- up-proj + scale + residual: 4 column-chunks of 512 ----
    // chunk c: wave computes local strip dloc in [wave*128, +128) for 16 tokens,
    // then stores 4 whole token rows of the chunk with 1 KB wave stores.
    const float scl = scale_p[0];
    float* stg = (float*)smem;              // [16][STGROW] fp32, block-shared
    #pragma unroll
    for (int c = 0; c < 4; ++c) {
        const int dbase = c * 512 + wave * 128;     // global d base of this wave's strip
        const int nt2_0 = dbase >> 4;
        #pragma unroll
        for (int t = 0; t < 8; ++t) {
            const int dd   = dbase + t * 16 + l15;  // global d column (this lane)
            const int dloc = wave * 128 + t * 16 + l15;
            const s16x8 b0 = ((const s16x8*)wubp)[((nt2_0 + t) * 2 + 0) * 64 + lane];
            const s16x8 b1 = ((const s16x8*)wubp)[((nt2_0 + t) * 2 + 1) * 64 + lane];
            f32x4 cc = (f32x4){0.f, 0.f, 0.f, 0.f};
            cc = __builtin_amdgcn_mfma_f32_16x16x32_bf16(afrag[0], b0, cc, 0, 0, 0);
            cc = __builtin_amdgcn_mfma_f32_16x16x32_bf16(afrag[1], b1, cc, 0, 0, 0);
            const float bun = bu[dd];
            #pragma unroll
            for (int reg = 0; reg < 4; ++reg)
                stg[(quad * 4 + reg) * STGROW + dloc] = scl * (cc[reg] + bun);
        }

        __syncthreads();   // chunk staged by all waves

        // store: wave owns token rows [wave*4, +4); per row 2x 1KB wave stores
        #pragma unroll
        for (int mi = 0; mi < 4; ++mi) {
            const int m = wave * 4 + mi;
            const size_t row = (size_t)(tok0 + m) * D + c * 512;
            #pragma unroll
            for (int c2 = 0; c2 < 2; ++c2) {
                const int dloc = c2 * 256 + lane * 4;
                const f32x4 v   = *(const f32x4*)&stg[m * STGROW + dloc];
                const float4 xv = *(const float4*)(x + row + dloc);
                f32x4 o;
                o[0] = v[0] + xv.x;
                o[1] = v[1] + xv.y;
                o[2] = v[2] + xv.z;
                o[3] = v[3] + xv.w;
                *(f32x4*)(out + row + dloc) = o;
            }
        }

        if (c < 3) __syncthreads();   // stores read before next chunk overwrites stg
    }
}

extern "C" void kernel_launch(void* const* d_in, const int* in_sizes, int n_in,
                              void* d_out, int out_size, void* d_ws, size_t ws_size,
                              hipStream_t stream) {
    const float* x     = (const float*)d_in[0];
    const float* gamma = (const float*)d_in[1];
    const float* beta  = (const float*)d_in[2];
    const float* wd    = (const float*)d_in[3];
    const float* bd    = (const float*)d_in[4];
    const float* wu    = (const float*)d_in[5];
    const float* bu    = (const float*)d_in[6];
    const float* scl   = (const float*)d_in[7];
    float* out = (float*)d_out;

    unsigned short* wdbp = (unsigned short*)d_ws;                // R*D bf16, frag-major
    unsigned short* wubp = wdbp + (size_t)R * D;                 // D*R bf16, frag-major
    float* u  = (float*)(wubp + (size_t)D * R);                  // R fp32
    float* cb = u + R;                                           // R fp32

    convert_pack<<<(R * D / 8) / 256, 256, 0, stream>>>(wd, wu, wdbp, wubp);
    prep_uc<<<R, 256, 0, stream>>>(wd, gamma, beta, bd, u, cb);
    adapter_mfma<<<NTOK / 16, 256, 0, stream>>>(x, gamma, wdbp, wubp, u, cb, bu, scl, out);
}